// Round 10
// baseline (197.657 us; speedup 1.0000x reference)
//
#include <hip/hip_runtime.h>
#include <hip/hip_bf16.h>
#include <cstdint>
#include <cstddef>

#define B_   2
#define N_   6
#define FD_  128
#define DIM_ 128
#define H_   64
#define W_   176
#define P_   (H_*W_)      // 11264
#define IMGW 704.0
#define IMGH 256.0
#define UVB  8            // uv blocks per (b,n)

struct __align__(16) Samp { float wx, wy; int o00, o01; int o10, o11; int valid, pad; };

typedef __attribute__((ext_vector_type(8))) short short8;
typedef __attribute__((ext_vector_type(4))) float f32x4;

// bf16 convert via HW cvt (compiler fuses pairs into v_cvt_pk_bf16_f32)
__device__ __forceinline__ unsigned short f2bf(float f) {
  union { __hip_bfloat16 h; unsigned short u; } c;
  c.h = __float2bfloat16(f);
  return c.u;
}
__device__ __forceinline__ float bf2f(unsigned short s) {
  return __uint_as_float(((unsigned int)s) << 16);
}
__device__ __forceinline__ float bfx(uint2 u, int j) {   // j-th bf16 of an 8B pack (j compile-time)
  unsigned int w = (j < 2) ? u.x : u.y;
  return bf2f((unsigned short)((j & 1) ? (w >> 16) : (w & 0xffffu)));
}

// ---------------- Kernel A: fp64 homography -> sample descriptors; BN fold; weight pre-swizzles ----------------
// blocks 0..95: uv work (8 blocks per bn). blocks 96..135: wprep — 160 frags x 64 lanes, single bf16:
//   f in [0,64): w1b, f in [64,128): w2b, f in [128,160): cwb (conv weights).
__global__ __launch_bounds__(256) void prep_kernel(const float* __restrict__ I_src, const float* __restrict__ I_tar_inv,
                           const float* __restrict__ E, const float* __restrict__ dis,
                           const float* __restrict__ nrm,
                           const float* __restrict__ bn_g, const float* __restrict__ bn_b,
                           const float* __restrict__ bn_m, const float* __restrict__ bn_v,
                           const float* __restrict__ w1, const float* __restrict__ w2,
                           const float* __restrict__ conv_w,
                           Samp* __restrict__ samp, float* __restrict__ bns, float* __restrict__ bnb,
                           short* __restrict__ w1b, short* __restrict__ w2b, short* __restrict__ cwb) {
  int blk = blockIdx.x;
  if (blk >= B_ * N_ * UVB) {
    int tid = (blk - B_ * N_ * UVB) * 256 + threadIdx.x;   // 0..10239
    int f = tid >> 6, l = tid & 63;
    if (f < 64) {
      int nt = f >> 2, ks = f & 3;
      int n = nt * 16 + (l & 15);
      int kb = ks * 32 + (l >> 4) * 8;
#pragma unroll
      for (int j = 0; j < 8; ++j)
        w1b[((size_t)f * 64 + l) * 8 + j] = (short)f2bf(w1[(size_t)(kb + j) * 256 + n]);
    } else if (f < 128) {
      int g = f - 64;
      int nt = g >> 3, ks = g & 7;
      int n = nt * 16 + (l & 15);
      int kb = ks * 32 + (l >> 4) * 8;
#pragma unroll
      for (int j = 0; j < 8; ++j)
        w2b[((size_t)g * 64 + l) * 8 + j] = (short)f2bf(w2[(size_t)(kb + j) * 128 + n]);
    } else {
      int g2 = f - 128;              // 0..31 -> (ot, ks) for conv frags
      int ot = g2 >> 2, ks = g2 & 3;
      int o  = ot * 16 + (l & 15);
      int cb = ks * 32 + (l >> 4) * 8;
#pragma unroll
      for (int j = 0; j < 8; ++j)
        cwb[((size_t)g2 * 64 + l) * 8 + j] = (short)f2bf(conv_w[(size_t)o * FD_ + cb + j]);
    }
    return;
  }
  int bn = blk / UVB;             // 0..11
  int part = blk % UVB;           // 0..7
  int bb = bn / N_;
  if (blk == 0 && threadIdx.x < FD_) {
    int t = threadIdx.x;
    float inv = 1.0f / sqrtf(bn_v[t] + 1e-5f);
    float sc = bn_g[t] * inv;
    bns[t] = sc;
    bnb[t] = bn_b[t] - bn_m[t] * sc;
  }
  const float* Ep = E + bn * 16;
  double R[9], T[3];
#pragma unroll
  for (int i = 0; i < 3; ++i) {
#pragma unroll
    for (int j = 0; j < 3; ++j) R[i*3+j] = (double)Ep[i*4+j];
    T[i] = (double)Ep[i*4+3];
  }
  double dd = (double)dis[bb];
  double M[9];
#pragma unroll
  for (int i = 0; i < 3; ++i)
#pragma unroll
    for (int j = 0; j < 3; ++j)
      M[i*3+j] = R[i*3+j] - T[i] * (double)nrm[bb*3+j] / dd;
  const float* Is = I_src + bn * 9;
  double A[9];
#pragma unroll
  for (int i = 0; i < 3; ++i)
#pragma unroll
    for (int j = 0; j < 3; ++j)
      A[i*3+j] = (double)Is[i*3+0]*M[0+j] + (double)Is[i*3+1]*M[3+j] + (double)Is[i*3+2]*M[6+j];
  const float* It = I_tar_inv + bb * 9;
  double Hm[9];
#pragma unroll
  for (int i = 0; i < 3; ++i)
#pragma unroll
    for (int j = 0; j < 3; ++j)
      Hm[i*3+j] = A[i*3+0]*(double)It[0+j] + A[i*3+1]*(double)It[3+j] + A[i*3+2]*(double)It[6+j];

  const double dx = 1.0 / (double)(W_ - 1);
  const double dy = 1.0 / (double)(H_ - 1);
  for (int p = part * 256 + threadIdx.x; p < P_; p += 256 * UVB) {
    int ii = p / W_;
    int jj = p - ii * W_;
    double xs = (jj == W_ - 1) ? 1.0 : (double)jj * dx;   // np.linspace exact endpoint
    double ys = (ii == H_ - 1) ? 1.0 : (double)ii * dy;
    double px = xs * IMGW;
    double py = ys * IMGH;
    double hx = Hm[0]*px + Hm[1]*py + Hm[2];
    double hy = Hm[3]*px + Hm[4]*py + Hm[5];
    double hz = Hm[6]*px + Hm[7]*py + Hm[8];
    double u = ((hx / hz) / IMGW) * (double)W_;
    double v = ((hy / hz) / IMGH) * (double)H_;
    double x0 = floor(u), y0 = floor(v);
    bool valid = (u >= 0.0) && (u <= (double)(W_ - 1)) && (v >= 0.0) && (v <= (double)(H_ - 1));
    int x0i = min(max((int)x0, 0), W_ - 1);
    int x1i = min(x0i + 1, W_ - 1);
    int y0i = min(max((int)y0, 0), H_ - 1);
    int y1i = min(y0i + 1, H_ - 1);
    Samp s;
    s.wx = (float)(u - x0);
    s.wy = (float)(v - y0);
    s.o00 = (y0i * W_ + x0i) * DIM_;
    s.o01 = (y0i * W_ + x1i) * DIM_;
    s.o10 = (y1i * W_ + x0i) * DIM_;
    s.o11 = (y1i * W_ + x1i) * DIM_;
    s.valid = valid ? 1 : 0;
    s.pad = 0;
    samp[(size_t)bn * P_ + p] = s;
  }
}

// ---------------- Kernel B: BN+ReLU+1x1 conv as bf16 MFMA -> val_t[bn][p][o] in BF16 ----------------
// No-LDS variant: A-fragments loaded DIRECTLY from global feature, BN+ReLU+hi/lo split in registers.
// Weights (cwb, pre-swizzled bf16, 32 KB, L1-resident) as B operand; round-0 store pattern.
__global__ __launch_bounds__(256) void conv_kernel(const float* __restrict__ feature,
    const short* __restrict__ cwb, const float* __restrict__ bns_g, const float* __restrict__ bnb_g,
    unsigned short* __restrict__ val_t) {
  __shared__ float bns_s[FD_], bnb_s[FD_];
  int t = threadIdx.x;
  if (t < FD_) { bns_s[t] = bns_g[t]; bnb_s[t] = bnb_g[t]; }
  __syncthreads();

  int bn = blockIdx.y;
  int p0 = blockIdx.x * 64;
  int lane = t & 63, wv = t >> 6;
  int m = lane & 15, quad = lane >> 4;
  int pw = wv * 16;

  const float* fb = feature + (size_t)bn * FD_ * P_ + p0 + pw + m;

  float xv[4][8];
#pragma unroll
  for (int ks = 0; ks < 4; ++ks)
#pragma unroll
    for (int j = 0; j < 8; ++j) {
      int c = ks * 32 + quad * 8 + j;
      xv[ks][j] = fb[(size_t)c * P_];
    }

  short8 Ah[4], Al[4];
#pragma unroll
  for (int ks = 0; ks < 4; ++ks)
#pragma unroll
    for (int j = 0; j < 8; ++j) {
      int c = ks * 32 + quad * 8 + j;
      float v = fmaxf(xv[ks][j] * bns_s[c] + bnb_s[c], 0.f);
      unsigned short h = f2bf(v);
      Ah[ks][j] = (short)h;
      Al[ks][j] = (short)f2bf(v - bf2f(h));
    }

  f32x4 acc[8];
#pragma unroll
  for (int ot = 0; ot < 8; ++ot) {
    f32x4 a = {0.f, 0.f, 0.f, 0.f};
#pragma unroll
    for (int ks = 0; ks < 4; ++ks) {
      short8 Bv = *(const short8*)(cwb + ((size_t)(ot * 4 + ks) * 64 + lane) * 8);
      a = __builtin_amdgcn_mfma_f32_16x16x32_bf16(Ah[ks], Bv, a, 0, 0, 0);
      a = __builtin_amdgcn_mfma_f32_16x16x32_bf16(Al[ks], Bv, a, 0, 0, 0);
    }
    acc[ot] = a;
  }

  unsigned short* vb = val_t + ((size_t)bn * P_ + p0 + pw + quad * 4) * DIM_ + m;
#pragma unroll
  for (int ot = 0; ot < 8; ++ot)
#pragma unroll
    for (int r = 0; r < 4; ++r)
      vb[(size_t)r * DIM_ + ot * 16] = f2bf(acc[ot][r]);
}

// ---------------- Kernel C+D fused: bilinear attention + LN1 + MLP + LN2 — one 16-px tile per block ----
// 512 thr = 8 waves. Attn phase: wave handles 2 px (32-lane groups, 4 dims/lane, round-7 structure),
// LN1 result -> LDS zl[16][132]. MLP phase: 8-way intra-tile split — wave wv owns GEMM1 nt {2wv,2wv+1}
// and GEMM2 dt = wv (full K, no acc reduction). LN2 via per-wave partials in pbuf. 4 barriers.
// LDS 26368 B; grid 1408 x 512 = 11264 waves (occupancy cap). Saves zln round-trip (34.5 MB) + 1 launch.
__global__ __launch_bounds__(512) void attn_mlp_kernel(const unsigned short* __restrict__ val_t,
    const Samp* __restrict__ samp,
    const float* __restrict__ ln1g, const float* __restrict__ ln1b,
    const short* __restrict__ w1b, const short* __restrict__ w2b,
    const float* __restrict__ b1, const float* __restrict__ b2,
    const float* __restrict__ ln2g, const float* __restrict__ ln2b,
    float* __restrict__ out) {
  __shared__ __align__(16) char smem[26368];
  float* zl   = (float*)smem;             // [16][132] floats, 8448 B
  short* hh   = (short*)(smem + 8448);    // [16][264] shorts, 8448 B
  short* hl   = (short*)(smem + 16896);   // [16][264] shorts, 8448 B
  float* pbuf = (float*)(smem + 25344);   // 256 floats (sums, sumsq)
  float* zo   = (float*)smem;             // [128][20] floats, 10240 B (overlay after B2)

  int t = threadIdx.x;
  int l = t & 63, wv = t >> 6;           // 8 waves
  int half = l >> 5, sl = l & 31;
  int m = l & 15, quad = (l >> 4) & 3;
  int bid = blockIdx.x;
  int newbid = (bid & 7) * (gridDim.x >> 3) + (bid >> 3);   // XCD swizzle (1408 % 8 == 0)
  int row0 = newbid * 16;

  // ================= attn phase: 2 px per wave =================
  int pt = row0 + wv * 2 + half;          // tile never straddles bb (P_ % 16 == 0)
  int bb = pt / P_;
  int p = pt - bb * P_;
  int d0 = sl << 2;

  uint2 uq = *(const uint2*)(val_t + ((size_t)(bb * N_) * P_ + p) * DIM_ + d0);
  float qv[4] = { bfx(uq, 0), bfx(uq, 1), bfx(uq, 2), bfx(uq, 3) };
  float qss = qv[0]*qv[0] + qv[1]*qv[1] + qv[2]*qv[2] + qv[3]*qv[3];
#pragma unroll
  for (int off = 1; off <= 16; off <<= 1) qss += __shfl_xor(qss, off, 64);
  float qinv = 1.0f / fmaxf(sqrtf(qss), 1e-12f);

  float dots[N_], vs[N_][4];
#pragma unroll
  for (int n = 0; n < N_; ++n) {
    Samp s = samp[(size_t)(bb * N_ + n) * P_ + p];
    const unsigned short* base = val_t + (size_t)(bb * N_ + n) * P_ * DIM_ + d0;
    uint2 u00 = *(const uint2*)(base + s.o00);
    uint2 u01 = *(const uint2*)(base + s.o01);
    uint2 u10 = *(const uint2*)(base + s.o10);
    uint2 u11 = *(const uint2*)(base + s.o11);
    float wx = s.wx, wy = s.wy;
    float w00 = (1.0f - wx) * (1.0f - wy), w01 = wx * (1.0f - wy);
    float w10 = (1.0f - wx) * wy,          w11 = wx * wy;
    float ss = 0.f, du = 0.f;
#pragma unroll
    for (int j = 0; j < 4; ++j) {
      float v = bfx(u00, j) * w00 + bfx(u01, j) * w01 + bfx(u10, j) * w10 + bfx(u11, j) * w11;
      vs[n][j] = v;
      ss += v * v;
      du += qv[j] * v;
    }
#pragma unroll
    for (int off = 1; off <= 16; off <<= 1) {
      ss += __shfl_xor(ss, off, 64);
      du += __shfl_xor(du, off, 64);
    }
    float kinv = 1.0f / fmaxf(sqrtf(ss), 1e-12f);
    dots[n] = s.valid ? (du * kinv * qinv) : 0.0f;
  }
  float mx = dots[0];
#pragma unroll
  for (int n = 1; n < N_; ++n) mx = fmaxf(mx, dots[n]);
  float es[N_], den = 0.f;
#pragma unroll
  for (int n = 0; n < N_; ++n) { es[n] = expf(dots[n] - mx); den += es[n]; }
  float dinv = 1.0f / den;
  float z[4] = { qv[0], qv[1], qv[2], qv[3] };
#pragma unroll
  for (int n = 0; n < N_; ++n) {
    float a = es[n] * dinv;
#pragma unroll
    for (int j = 0; j < 4; ++j) z[j] += a * vs[n][j];
  }
  float sz = z[0] + z[1] + z[2] + z[3];
  float q2 = z[0]*z[0] + z[1]*z[1] + z[2]*z[2] + z[3]*z[3];
#pragma unroll
  for (int off = 1; off <= 16; off <<= 1) {
    sz += __shfl_xor(sz, off, 64);
    q2 += __shfl_xor(q2, off, 64);
  }
  float mean1 = sz * (1.0f / DIM_);
  float var1 = fmaxf(q2 * (1.0f / DIM_) - mean1 * mean1, 0.f);
  float rstd1 = rsqrtf(var1 + 1e-5f);
  float4 g4 = *(const float4*)(ln1g + d0);
  float4 b4 = *(const float4*)(ln1b + d0);
  float4 o4;
  o4.x = (z[0] - mean1) * rstd1 * g4.x + b4.x;
  o4.y = (z[1] - mean1) * rstd1 * g4.y + b4.y;
  o4.z = (z[2] - mean1) * rstd1 * g4.z + b4.z;
  o4.w = (z[3] - mean1) * rstd1 * g4.w + b4.w;
  *(float4*)&zl[(wv * 2 + half) * 132 + d0] = o4;
  __syncthreads();   // B0: zl tile complete

  // ================= mlp phase: 8-way intra-tile split =================
  // per-wave constants (dt = wv; nt = 2wv, 2wv+1)
  float b1v[2];
  b1v[0] = b1[(wv * 2 + 0) * 16 + m];
  b1v[1] = b1[(wv * 2 + 1) * 16 + m];
  int dd = wv * 16 + m;
  float b2v = b2[dd], g2v = ln2g[dd], be2v = ln2b[dd];

  // A1 frags from zl row m; residual from zl rows quad*4+r at col dd
  short8 A1h[4], A1l[4];
  const float* zr0 = &zl[m * 132];
#pragma unroll
  for (int ks = 0; ks < 4; ++ks) {
#pragma unroll
    for (int j = 0; j < 8; ++j) {
      float v = zr0[ks * 32 + quad * 8 + j];
      unsigned short h = f2bf(v);
      A1h[ks][j] = (short)h;
      A1l[ks][j] = (short)f2bf(v - bf2f(h));
    }
  }
  float res[4];
#pragma unroll
  for (int r = 0; r < 4; ++r)
    res[r] = zl[(quad * 4 + r) * 132 + dd];

  // ---- GEMM1: 2 hidden tiles -> shared hdn ----
#pragma unroll
  for (int i = 0; i < 2; ++i) {
    int nt = wv * 2 + i;
    f32x4 a = {0.f, 0.f, 0.f, 0.f};
#pragma unroll
    for (int ks = 0; ks < 4; ++ks) {
      short8 Bv = *(const short8*)(w1b + ((size_t)(nt * 4 + ks) * 64 + l) * 8);
      a = __builtin_amdgcn_mfma_f32_16x16x32_bf16(A1h[ks], Bv, a, 0, 0, 0);
      a = __builtin_amdgcn_mfma_f32_16x16x32_bf16(A1l[ks], Bv, a, 0, 0, 0);
    }
#pragma unroll
    for (int r = 0; r < 4; ++r) {
      float hv = a[r] + b1v[i];
      float g = 0.5f * hv * (1.0f + erff(hv * 0.70710678118654752f));
      unsigned short gh = f2bf(g);
      int addr = (quad * 4 + r) * 264 + nt * 16 + m;
      hh[addr] = (short)gh;
      hl[addr] = (short)f2bf(g - bf2f(gh));
    }
  }
  __syncthreads();   // B1: hdn complete

  // ---- GEMM2: dt = wv, full K=256 ----
  f32x4 acc2 = {0.f, 0.f, 0.f, 0.f};
#pragma unroll
  for (int ks2 = 0; ks2 < 8; ++ks2) {
    short8 A2h = *(const short8*)&hh[m * 264 + ks2 * 32 + quad * 8];
    short8 A2l = *(const short8*)&hl[m * 264 + ks2 * 32 + quad * 8];
    short8 Bv = *(const short8*)(w2b + ((size_t)(wv * 8 + ks2) * 64 + l) * 8);
    acc2 = __builtin_amdgcn_mfma_f32_16x16x32_bf16(A2h, Bv, acc2, 0, 0, 0);
    acc2 = __builtin_amdgcn_mfma_f32_16x16x32_bf16(A2l, Bv, acc2, 0, 0, 0);
  }

  float z2[4];
#pragma unroll
  for (int r = 0; r < 4; ++r)
    z2[r] = acc2[r] + b2v + res[r];

  // ---- LN2: per-wave partials over its 16 dims (reduce over m) ----
  float ps[4], pq[4];
#pragma unroll
  for (int r = 0; r < 4; ++r) {
    float s = z2[r], q = z2[r] * z2[r];
#pragma unroll
    for (int off = 1; off <= 8; off <<= 1) {
      s += __shfl_xor(s, off, 64);
      q += __shfl_xor(q, off, 64);
    }
    ps[r] = s; pq[r] = q;
  }
  if (m == 0) {
#pragma unroll
    for (int r = 0; r < 4; ++r) {
      pbuf[wv * 16 + quad * 4 + r]       = ps[r];
      pbuf[128 + wv * 16 + quad * 4 + r] = pq[r];
    }
  }
  __syncthreads();   // B2 (also: hdn reads done before zo overlay)

  float mean[4], rstd[4];
#pragma unroll
  for (int r = 0; r < 4; ++r) {
    int px = quad * 4 + r;
    float s = 0.f, q = 0.f;
#pragma unroll
    for (int w = 0; w < 8; ++w) {
      s += pbuf[w * 16 + px];
      q += pbuf[128 + w * 16 + px];
    }
    mean[r] = s * (1.0f / 128.0f);
    float var = fmaxf(q * (1.0f / 128.0f) - mean[r] * mean[r], 0.f);
    rstd[r] = rsqrtf(var + 1e-5f);
  }

  // ---- normalize + transpose via zo ----
#pragma unroll
  for (int r = 0; r < 4; ++r) {
    float v = (z2[r] - mean[r]) * rstd[r] * g2v + be2v;
    zo[(wv * 16 + m) * 20 + quad * 4 + r] = v;
  }
  __syncthreads();   // B3

  // coalesced transposed store: out[b][d][p], 16 px per block (512 thr cover 128 d x 4 quads exactly)
  int bb2 = row0 / P_;
  int p0 = row0 - bb2 * P_;
  float* ob = out + (size_t)bb2 * DIM_ * P_ + p0;
  {
    int d = t >> 2, fq = t & 3;
    float4 v4 = *(float4*)&zo[d * 20 + fq * 4];
    *(float4*)(ob + (size_t)d * P_ + fq * 4) = v4;
  }
}

extern "C" void kernel_launch(void* const* d_in, const int* in_sizes, int n_in,
                              void* d_out, int out_size, void* d_ws, size_t ws_size,
                              hipStream_t stream) {
  const float* feature = (const float*)d_in[0];
  const float* I_src   = (const float*)d_in[1];
  const float* I_tar   = (const float*)d_in[2];
  const float* E       = (const float*)d_in[3];
  const float* dis     = (const float*)d_in[4];
  const float* nrm     = (const float*)d_in[5];
  const float* conv_w  = (const float*)d_in[6];
  const float* bn_g    = (const float*)d_in[7];
  const float* bn_b    = (const float*)d_in[8];
  const float* bn_m    = (const float*)d_in[9];
  const float* bn_v    = (const float*)d_in[10];
  const float* ln1g    = (const float*)d_in[11];
  const float* ln1b    = (const float*)d_in[12];
  const float* ln2g    = (const float*)d_in[13];
  const float* ln2b    = (const float*)d_in[14];
  const float* w1      = (const float*)d_in[15];
  const float* b1      = (const float*)d_in[16];
  const float* w2      = (const float*)d_in[17];
  const float* b2      = (const float*)d_in[18];
  float* out = (float*)d_out;

  float* wsf = (float*)d_ws;
  float* bns = wsf;                   // 128
  float* bnb = wsf + 128;             // 128
  unsigned short* val_t = (unsigned short*)(wsf + 256);          // B*N*P*DIM bf16 (34.6 MB)
  float* zln = (float*)(val_t + (size_t)B_ * N_ * P_ * DIM_);    // (unused after fusion; layout kept)
  Samp*  samp = (Samp*)(zln + (size_t)B_ * P_ * DIM_);           // 12*P structs (32B each)
  short* w1b = (short*)(samp + (size_t)B_ * N_ * P_);            // 32768 shorts
  short* w2b = w1b + 32768;                                      // 32768 shorts
  short* cwb = w2b + 32768;                                      // 16384 shorts (conv frags)

  hipLaunchKernelGGL(prep_kernel, dim3(B_ * N_ * UVB + 40), dim3(256), 0, stream,
                     I_src, I_tar, E, dis, nrm, bn_g, bn_b, bn_m, bn_v, w1, w2, conv_w,
                     samp, bns, bnb, w1b, w2b, cwb);
  hipLaunchKernelGGL(conv_kernel, dim3(P_ / 64, B_ * N_), dim3(256), 0, stream,
                     feature, cwb, bns, bnb, val_t);
  hipLaunchKernelGGL(attn_mlp_kernel, dim3(B_ * P_ / 16), dim3(512), 0, stream,
                     val_t, samp, ln1g, ln1b, w1b, w2b, b1, b2, ln2g, ln2b, out);
}

// Round 11
// 181.269 us; speedup vs baseline: 1.0904x; 1.0904x over previous
//
#include <hip/hip_runtime.h>
#include <hip/hip_bf16.h>
#include <cstdint>
#include <cstddef>

#define B_   2
#define N_   6
#define FD_  128
#define DIM_ 128
#define H_   64
#define W_   176
#define P_   (H_*W_)      // 11264
#define IMGW 704.0
#define IMGH 256.0
#define UVB  8            // uv blocks per (b,n)

struct __align__(16) Samp { float wx, wy; int o00, o01; int o10, o11; int valid, pad; };

typedef __attribute__((ext_vector_type(8))) short short8;
typedef __attribute__((ext_vector_type(4))) float f32x4;

// bf16 convert via HW cvt (compiler fuses pairs into v_cvt_pk_bf16_f32)
__device__ __forceinline__ unsigned short f2bf(float f) {
  union { __hip_bfloat16 h; unsigned short u; } c;
  c.h = __float2bfloat16(f);
  return c.u;
}
__device__ __forceinline__ float bf2f(unsigned short s) {
  return __uint_as_float(((unsigned int)s) << 16);
}
__device__ __forceinline__ float bfx8(uint4 u, int j) {  // j-th bf16 of a 16B pack (j compile-time)
  unsigned int w = (j < 2) ? u.x : (j < 4) ? u.y : (j < 6) ? u.z : u.w;
  return bf2f((unsigned short)((j & 1) ? (w >> 16) : (w & 0xffffu)));
}

// ---------------- Kernel A: fp64 homography -> sample descriptors; BN fold; weight pre-swizzles ----------------
// blocks 0..95: uv work (8 blocks per bn). blocks 96..135: wprep — 160 frags x 64 lanes, single bf16:
//   f in [0,64): w1b, f in [64,128): w2b, f in [128,160): cwb (conv weights).
__global__ __launch_bounds__(256) void prep_kernel(const float* __restrict__ I_src, const float* __restrict__ I_tar_inv,
                           const float* __restrict__ E, const float* __restrict__ dis,
                           const float* __restrict__ nrm,
                           const float* __restrict__ bn_g, const float* __restrict__ bn_b,
                           const float* __restrict__ bn_m, const float* __restrict__ bn_v,
                           const float* __restrict__ w1, const float* __restrict__ w2,
                           const float* __restrict__ conv_w,
                           Samp* __restrict__ samp, float* __restrict__ bns, float* __restrict__ bnb,
                           short* __restrict__ w1b, short* __restrict__ w2b, short* __restrict__ cwb) {
  int blk = blockIdx.x;
  if (blk >= B_ * N_ * UVB) {
    int tid = (blk - B_ * N_ * UVB) * 256 + threadIdx.x;   // 0..10239
    int f = tid >> 6, l = tid & 63;
    if (f < 64) {
      int nt = f >> 2, ks = f & 3;
      int n = nt * 16 + (l & 15);
      int kb = ks * 32 + (l >> 4) * 8;
#pragma unroll
      for (int j = 0; j < 8; ++j)
        w1b[((size_t)f * 64 + l) * 8 + j] = (short)f2bf(w1[(size_t)(kb + j) * 256 + n]);
    } else if (f < 128) {
      int g = f - 64;
      int nt = g >> 3, ks = g & 7;
      int n = nt * 16 + (l & 15);
      int kb = ks * 32 + (l >> 4) * 8;
#pragma unroll
      for (int j = 0; j < 8; ++j)
        w2b[((size_t)g * 64 + l) * 8 + j] = (short)f2bf(w2[(size_t)(kb + j) * 128 + n]);
    } else {
      int g2 = f - 128;              // 0..31 -> (ot, ks) for conv frags
      int ot = g2 >> 2, ks = g2 & 3;
      int o  = ot * 16 + (l & 15);
      int cb = ks * 32 + (l >> 4) * 8;
#pragma unroll
      for (int j = 0; j < 8; ++j)
        cwb[((size_t)g2 * 64 + l) * 8 + j] = (short)f2bf(conv_w[(size_t)o * FD_ + cb + j]);
    }
    return;
  }
  int bn = blk / UVB;             // 0..11
  int part = blk % UVB;           // 0..7
  int bb = bn / N_;
  if (blk == 0 && threadIdx.x < FD_) {
    int t = threadIdx.x;
    float inv = 1.0f / sqrtf(bn_v[t] + 1e-5f);
    float sc = bn_g[t] * inv;
    bns[t] = sc;
    bnb[t] = bn_b[t] - bn_m[t] * sc;
  }
  const float* Ep = E + bn * 16;
  double R[9], T[3];
#pragma unroll
  for (int i = 0; i < 3; ++i) {
#pragma unroll
    for (int j = 0; j < 3; ++j) R[i*3+j] = (double)Ep[i*4+j];
    T[i] = (double)Ep[i*4+3];
  }
  double dd = (double)dis[bb];
  double M[9];
#pragma unroll
  for (int i = 0; i < 3; ++i)
#pragma unroll
    for (int j = 0; j < 3; ++j)
      M[i*3+j] = R[i*3+j] - T[i] * (double)nrm[bb*3+j] / dd;
  const float* Is = I_src + bn * 9;
  double A[9];
#pragma unroll
  for (int i = 0; i < 3; ++i)
#pragma unroll
    for (int j = 0; j < 3; ++j)
      A[i*3+j] = (double)Is[i*3+0]*M[0+j] + (double)Is[i*3+1]*M[3+j] + (double)Is[i*3+2]*M[6+j];
  const float* It = I_tar_inv + bb * 9;
  double Hm[9];
#pragma unroll
  for (int i = 0; i < 3; ++i)
#pragma unroll
    for (int j = 0; j < 3; ++j)
      Hm[i*3+j] = A[i*3+0]*(double)It[0+j] + A[i*3+1]*(double)It[3+j] + A[i*3+2]*(double)It[6+j];

  const double dx = 1.0 / (double)(W_ - 1);
  const double dy = 1.0 / (double)(H_ - 1);
  for (int p = part * 256 + threadIdx.x; p < P_; p += 256 * UVB) {
    int ii = p / W_;
    int jj = p - ii * W_;
    double xs = (jj == W_ - 1) ? 1.0 : (double)jj * dx;   // np.linspace exact endpoint
    double ys = (ii == H_ - 1) ? 1.0 : (double)ii * dy;
    double px = xs * IMGW;
    double py = ys * IMGH;
    double hx = Hm[0]*px + Hm[1]*py + Hm[2];
    double hy = Hm[3]*px + Hm[4]*py + Hm[5];
    double hz = Hm[6]*px + Hm[7]*py + Hm[8];
    double u = ((hx / hz) / IMGW) * (double)W_;
    double v = ((hy / hz) / IMGH) * (double)H_;
    double x0 = floor(u), y0 = floor(v);
    bool valid = (u >= 0.0) && (u <= (double)(W_ - 1)) && (v >= 0.0) && (v <= (double)(H_ - 1));
    int x0i = min(max((int)x0, 0), W_ - 1);
    int x1i = min(x0i + 1, W_ - 1);
    int y0i = min(max((int)y0, 0), H_ - 1);
    int y1i = min(y0i + 1, H_ - 1);
    Samp s;
    s.wx = (float)(u - x0);
    s.wy = (float)(v - y0);
    s.o00 = (y0i * W_ + x0i) * DIM_;
    s.o01 = (y0i * W_ + x1i) * DIM_;
    s.o10 = (y1i * W_ + x0i) * DIM_;
    s.o11 = (y1i * W_ + x1i) * DIM_;
    s.valid = valid ? 1 : 0;
    s.pad = 0;
    samp[(size_t)bn * P_ + p] = s;
  }
}

// ---------------- Kernel B: BN+ReLU+1x1 conv as bf16 MFMA -> val_t[bn][p][o] in BF16 ----------------
// No-LDS variant: A-fragments loaded DIRECTLY from global feature, BN+ReLU+hi/lo split in registers.
// Weights (cwb, pre-swizzled bf16, 32 KB, L1-resident) as B operand; round-0 store pattern.
__global__ __launch_bounds__(256) void conv_kernel(const float* __restrict__ feature,
    const short* __restrict__ cwb, const float* __restrict__ bns_g, const float* __restrict__ bnb_g,
    unsigned short* __restrict__ val_t) {
  __shared__ float bns_s[FD_], bnb_s[FD_];
  int t = threadIdx.x;
  if (t < FD_) { bns_s[t] = bns_g[t]; bnb_s[t] = bnb_g[t]; }
  __syncthreads();

  int bn = blockIdx.y;
  int p0 = blockIdx.x * 64;
  int lane = t & 63, wv = t >> 6;
  int m = lane & 15, quad = lane >> 4;
  int pw = wv * 16;

  const float* fb = feature + (size_t)bn * FD_ * P_ + p0 + pw + m;

  float xv[4][8];
#pragma unroll
  for (int ks = 0; ks < 4; ++ks)
#pragma unroll
    for (int j = 0; j < 8; ++j) {
      int c = ks * 32 + quad * 8 + j;
      xv[ks][j] = fb[(size_t)c * P_];
    }

  short8 Ah[4], Al[4];
#pragma unroll
  for (int ks = 0; ks < 4; ++ks)
#pragma unroll
    for (int j = 0; j < 8; ++j) {
      int c = ks * 32 + quad * 8 + j;
      float v = fmaxf(xv[ks][j] * bns_s[c] + bnb_s[c], 0.f);
      unsigned short h = f2bf(v);
      Ah[ks][j] = (short)h;
      Al[ks][j] = (short)f2bf(v - bf2f(h));
    }

  f32x4 acc[8];
#pragma unroll
  for (int ot = 0; ot < 8; ++ot) {
    f32x4 a = {0.f, 0.f, 0.f, 0.f};
#pragma unroll
    for (int ks = 0; ks < 4; ++ks) {
      short8 Bv = *(const short8*)(cwb + ((size_t)(ot * 4 + ks) * 64 + lane) * 8);
      a = __builtin_amdgcn_mfma_f32_16x16x32_bf16(Ah[ks], Bv, a, 0, 0, 0);
      a = __builtin_amdgcn_mfma_f32_16x16x32_bf16(Al[ks], Bv, a, 0, 0, 0);
    }
    acc[ot] = a;
  }

  unsigned short* vb = val_t + ((size_t)bn * P_ + p0 + pw + quad * 4) * DIM_ + m;
#pragma unroll
  for (int ot = 0; ot < 8; ++ot)
#pragma unroll
    for (int r = 0; r < 4; ++r)
      vb[(size_t)r * DIM_ + ot * 16] = f2bf(acc[ot][r]);
}

// ---------------- Kernel C+D fused: attention + LN1 + MLP + LN2 — one 16-px tile per block ----------------
// 256 thr = 4 waves. Attn phase: 4 px per wave (16-lane groups, 8 dims/lane) — reductions are 4-round
// shfl_xor(1..8) butterflies; corner gathers are 16B uint4 (each VMEM instr serves a whole px-group).
// LN1 -> LDS zl[16][132]. MLP phase: round-8-proven 4-way split — wave wv owns GEMM1 nt {4wv..4wv+3}
// and GEMM2 dt {2wv, 2wv+1} (full K). LN2 via per-wave partials in pbuf. 4 barriers. LDS 25856 B.
__global__ __launch_bounds__(256) void attn_mlp_kernel(const unsigned short* __restrict__ val_t,
    const Samp* __restrict__ samp,
    const float* __restrict__ ln1g, const float* __restrict__ ln1b,
    const short* __restrict__ w1b, const short* __restrict__ w2b,
    const float* __restrict__ b1, const float* __restrict__ b2,
    const float* __restrict__ ln2g, const float* __restrict__ ln2b,
    float* __restrict__ out) {
  __shared__ __align__(16) char smem[25856];
  float* zl   = (float*)smem;             // [16][132] floats, 8448 B
  short* hh   = (short*)(smem + 8448);    // [16][264] shorts, 8448 B
  short* hl   = (short*)(smem + 16896);   // [16][264] shorts, 8448 B
  float* pbuf = (float*)(smem + 25344);   // 128 floats (sums, sumsq)
  float* zo   = (float*)smem;             // [128][20] floats, 10240 B (overlay after B2)

  int t = threadIdx.x;
  int l = t & 63, wv = t >> 6;           // 4 waves
  int pq = l >> 4, sl = l & 15;          // attn: px-of-4, sub-lane
  int m = l & 15, quad = l >> 4;         // mlp: MFMA roles (quad == pq)
  int bid = blockIdx.x;
  int newbid = (bid & 7) * (gridDim.x >> 3) + (bid >> 3);   // XCD swizzle (1408 % 8 == 0)
  int row0 = newbid * 16;

  // ================= attn phase: 4 px per wave, 8 dims per lane =================
  int pt = row0 + wv * 4 + pq;            // tile never straddles bb (P_ % 16 == 0)
  int bb = pt / P_;
  int p = pt - bb * P_;
  int d0 = sl << 3;                       // dims d0..d0+7

  uint4 uq = *(const uint4*)(val_t + ((size_t)(bb * N_) * P_ + p) * DIM_ + d0);
  float qv[8];
#pragma unroll
  for (int j = 0; j < 8; ++j) qv[j] = bfx8(uq, j);
  float qss = 0.f;
#pragma unroll
  for (int j = 0; j < 8; ++j) qss += qv[j] * qv[j];
#pragma unroll
  for (int off = 1; off <= 8; off <<= 1) qss += __shfl_xor(qss, off, 64);
  float qinv = 1.0f / fmaxf(sqrtf(qss), 1e-12f);

  float dots[N_], vs[N_][8];
#pragma unroll
  for (int n = 0; n < N_; ++n) {
    Samp s = samp[(size_t)(bb * N_ + n) * P_ + p];
    const unsigned short* base = val_t + (size_t)(bb * N_ + n) * P_ * DIM_ + d0;
    uint4 u00 = *(const uint4*)(base + s.o00);
    uint4 u01 = *(const uint4*)(base + s.o01);
    uint4 u10 = *(const uint4*)(base + s.o10);
    uint4 u11 = *(const uint4*)(base + s.o11);
    float wx = s.wx, wy = s.wy;
    float w00 = (1.0f - wx) * (1.0f - wy), w01 = wx * (1.0f - wy);
    float w10 = (1.0f - wx) * wy,          w11 = wx * wy;
    float ss = 0.f, du = 0.f;
#pragma unroll
    for (int j = 0; j < 8; ++j) {
      float v = bfx8(u00, j) * w00 + bfx8(u01, j) * w01 + bfx8(u10, j) * w10 + bfx8(u11, j) * w11;
      vs[n][j] = v;
      ss += v * v;
      du += qv[j] * v;
    }
#pragma unroll
    for (int off = 1; off <= 8; off <<= 1) {
      ss += __shfl_xor(ss, off, 64);
      du += __shfl_xor(du, off, 64);
    }
    float kinv = 1.0f / fmaxf(sqrtf(ss), 1e-12f);
    dots[n] = s.valid ? (du * kinv * qinv) : 0.0f;
  }
  float mx = dots[0];
#pragma unroll
  for (int n = 1; n < N_; ++n) mx = fmaxf(mx, dots[n]);
  float es[N_], den = 0.f;
#pragma unroll
  for (int n = 0; n < N_; ++n) { es[n] = expf(dots[n] - mx); den += es[n]; }
  float dinv = 1.0f / den;
  float z[8];
#pragma unroll
  for (int j = 0; j < 8; ++j) z[j] = qv[j];
#pragma unroll
  for (int n = 0; n < N_; ++n) {
    float a = es[n] * dinv;
#pragma unroll
    for (int j = 0; j < 8; ++j) z[j] += a * vs[n][j];
  }
  // LN1: joint (sum, sumsq), 4-round reduction over the 16-lane group (16 lanes x 8 dims = 128)
  float sz = 0.f, q2 = 0.f;
#pragma unroll
  for (int j = 0; j < 8; ++j) { sz += z[j]; q2 += z[j] * z[j]; }
#pragma unroll
  for (int off = 1; off <= 8; off <<= 1) {
    sz += __shfl_xor(sz, off, 64);
    q2 += __shfl_xor(q2, off, 64);
  }
  float mean1 = sz * (1.0f / DIM_);
  float var1 = fmaxf(q2 * (1.0f / DIM_) - mean1 * mean1, 0.f);
  float rstd1 = rsqrtf(var1 + 1e-5f);
  float4 ga = *(const float4*)(ln1g + d0);
  float4 gb = *(const float4*)(ln1g + d0 + 4);
  float4 ba = *(const float4*)(ln1b + d0);
  float4 bbv = *(const float4*)(ln1b + d0 + 4);
  float4 oa, ob4;
  oa.x  = (z[0] - mean1) * rstd1 * ga.x + ba.x;
  oa.y  = (z[1] - mean1) * rstd1 * ga.y + ba.y;
  oa.z  = (z[2] - mean1) * rstd1 * ga.z + ba.z;
  oa.w  = (z[3] - mean1) * rstd1 * ga.w + ba.w;
  ob4.x = (z[4] - mean1) * rstd1 * gb.x + bbv.x;
  ob4.y = (z[5] - mean1) * rstd1 * gb.y + bbv.y;
  ob4.z = (z[6] - mean1) * rstd1 * gb.z + bbv.z;
  ob4.w = (z[7] - mean1) * rstd1 * gb.w + bbv.w;
  float* zrow = &zl[(wv * 4 + pq) * 132 + d0];
  *(float4*)zrow = oa;
  *(float4*)(zrow + 4) = ob4;
  __syncthreads();   // B0: zl tile complete

  // ================= mlp phase: 4-way intra-tile split (round-8 structure) =================
  float b1v[4];
#pragma unroll
  for (int i = 0; i < 4; ++i) b1v[i] = b1[(wv * 4 + i) * 16 + m];
  float res[2][4], b2v[2], g2v[2], be2v[2];
#pragma unroll
  for (int e = 0; e < 2; ++e) {
    int dt = wv * 2 + e;
    int d = dt * 16 + m;
    b2v[e] = b2[d]; g2v[e] = ln2g[d]; be2v[e] = ln2b[d];
#pragma unroll
    for (int r = 0; r < 4; ++r)
      res[e][r] = zl[(quad * 4 + r) * 132 + dt * 16 + m];
  }

  // A1 frags (hi/lo) from zl row m
  short8 A1h[4], A1l[4];
  const float* zr0 = &zl[m * 132];
#pragma unroll
  for (int ks = 0; ks < 4; ++ks) {
#pragma unroll
    for (int j = 0; j < 8; ++j) {
      float v = zr0[ks * 32 + quad * 8 + j];
      unsigned short h = f2bf(v);
      A1h[ks][j] = (short)h;
      A1l[ks][j] = (short)f2bf(v - bf2f(h));
    }
  }

  // ---- GEMM1: 4 hidden tiles -> shared hdn ----
#pragma unroll
  for (int i = 0; i < 4; ++i) {
    int nt = wv * 4 + i;
    f32x4 a = {0.f, 0.f, 0.f, 0.f};
#pragma unroll
    for (int ks = 0; ks < 4; ++ks) {
      short8 Bv = *(const short8*)(w1b + ((size_t)(nt * 4 + ks) * 64 + l) * 8);
      a = __builtin_amdgcn_mfma_f32_16x16x32_bf16(A1h[ks], Bv, a, 0, 0, 0);
      a = __builtin_amdgcn_mfma_f32_16x16x32_bf16(A1l[ks], Bv, a, 0, 0, 0);
    }
#pragma unroll
    for (int r = 0; r < 4; ++r) {
      float hv = a[r] + b1v[i];
      float g = 0.5f * hv * (1.0f + erff(hv * 0.70710678118654752f));
      unsigned short gh = f2bf(g);
      int addr = (quad * 4 + r) * 264 + nt * 16 + m;
      hh[addr] = (short)gh;
      hl[addr] = (short)f2bf(g - bf2f(gh));
    }
  }
  __syncthreads();   // B1: hdn complete

  // ---- GEMM2: 2 output dt, full K=256 ----
  f32x4 acc2[2];
  acc2[0] = (f32x4){0.f, 0.f, 0.f, 0.f};
  acc2[1] = (f32x4){0.f, 0.f, 0.f, 0.f};
#pragma unroll
  for (int ks2 = 0; ks2 < 8; ++ks2) {
    short8 A2h = *(const short8*)&hh[m * 264 + ks2 * 32 + quad * 8];
    short8 A2l = *(const short8*)&hl[m * 264 + ks2 * 32 + quad * 8];
#pragma unroll
    for (int e = 0; e < 2; ++e) {
      int g = (wv * 2 + e) * 8 + ks2;
      short8 Bv = *(const short8*)(w2b + ((size_t)g * 64 + l) * 8);
      acc2[e] = __builtin_amdgcn_mfma_f32_16x16x32_bf16(A2h, Bv, acc2[e], 0, 0, 0);
      acc2[e] = __builtin_amdgcn_mfma_f32_16x16x32_bf16(A2l, Bv, acc2[e], 0, 0, 0);
    }
  }

  float z2[2][4];
#pragma unroll
  for (int e = 0; e < 2; ++e)
#pragma unroll
    for (int r = 0; r < 4; ++r)
      z2[e][r] = acc2[e][r] + b2v[e] + res[e][r];

  // ---- LN2: per-wave partials over its 32 dims (reduce over m) ----
  float ps[4], pq2[4];
#pragma unroll
  for (int r = 0; r < 4; ++r) {
    float s = z2[0][r] + z2[1][r];
    float q = z2[0][r]*z2[0][r] + z2[1][r]*z2[1][r];
#pragma unroll
    for (int off = 1; off <= 8; off <<= 1) {
      s += __shfl_xor(s, off, 64);
      q += __shfl_xor(q, off, 64);
    }
    ps[r] = s; pq2[r] = q;
  }
  if (m == 0) {
#pragma unroll
    for (int r = 0; r < 4; ++r) {
      pbuf[wv * 16 + quad * 4 + r]      = ps[r];
      pbuf[64 + wv * 16 + quad * 4 + r] = pq2[r];
    }
  }
  __syncthreads();   // B2 (also: hdn reads done before zo overlay)

  float mean[4], rstd[4];
#pragma unroll
  for (int r = 0; r < 4; ++r) {
    int px = quad * 4 + r;
    float s = pbuf[px] + pbuf[16 + px] + pbuf[32 + px] + pbuf[48 + px];
    float q = pbuf[64 + px] + pbuf[80 + px] + pbuf[96 + px] + pbuf[112 + px];
    mean[r] = s * (1.0f / 128.0f);
    float var = fmaxf(q * (1.0f / 128.0f) - mean[r] * mean[r], 0.f);
    rstd[r] = rsqrtf(var + 1e-5f);
  }

  // ---- normalize + transpose via zo (disjoint from pbuf) ----
#pragma unroll
  for (int e = 0; e < 2; ++e) {
    int dt = wv * 2 + e;
#pragma unroll
    for (int r = 0; r < 4; ++r) {
      float v = (z2[e][r] - mean[r]) * rstd[r] * g2v[e] + be2v[e];
      zo[(dt * 16 + m) * 20 + quad * 4 + r] = v;
    }
  }
  __syncthreads();   // B3

  // coalesced transposed store: out[b][d][p], 16 px per block
  int bb2 = row0 / P_;
  int p0 = row0 - bb2 * P_;
  float* ob = out + (size_t)bb2 * DIM_ * P_ + p0;
#pragma unroll
  for (int pass = 0; pass < 2; ++pass) {
    int idx = pass * 256 + t;     // 0..511
    int d = idx >> 2, fq = idx & 3;
    float4 v4 = *(float4*)&zo[d * 20 + fq * 4];
    *(float4*)(ob + (size_t)d * P_ + fq * 4) = v4;
  }
}

extern "C" void kernel_launch(void* const* d_in, const int* in_sizes, int n_in,
                              void* d_out, int out_size, void* d_ws, size_t ws_size,
                              hipStream_t stream) {
  const float* feature = (const float*)d_in[0];
  const float* I_src   = (const float*)d_in[1];
  const float* I_tar   = (const float*)d_in[2];
  const float* E       = (const float*)d_in[3];
  const float* dis     = (const float*)d_in[4];
  const float* nrm     = (const float*)d_in[5];
  const float* conv_w  = (const float*)d_in[6];
  const float* bn_g    = (const float*)d_in[7];
  const float* bn_b    = (const float*)d_in[8];
  const float* bn_m    = (const float*)d_in[9];
  const float* bn_v    = (const float*)d_in[10];
  const float* ln1g    = (const float*)d_in[11];
  const float* ln1b    = (const float*)d_in[12];
  const float* ln2g    = (const float*)d_in[13];
  const float* ln2b    = (const float*)d_in[14];
  const float* w1      = (const float*)d_in[15];
  const float* b1      = (const float*)d_in[16];
  const float* w2      = (const float*)d_in[17];
  const float* b2      = (const float*)d_in[18];
  float* out = (float*)d_out;

  float* wsf = (float*)d_ws;
  float* bns = wsf;                   // 128
  float* bnb = wsf + 128;             // 128
  unsigned short* val_t = (unsigned short*)(wsf + 256);          // B*N*P*DIM bf16 (34.6 MB)
  float* zln = (float*)(val_t + (size_t)B_ * N_ * P_ * DIM_);    // (unused after fusion; layout kept)
  Samp*  samp = (Samp*)(zln + (size_t)B_ * P_ * DIM_);           // 12*P structs (32B each)
  short* w1b = (short*)(samp + (size_t)B_ * N_ * P_);            // 32768 shorts
  short* w2b = w1b + 32768;                                      // 32768 shorts
  short* cwb = w2b + 32768;                                      // 16384 shorts (conv frags)

  hipLaunchKernelGGL(prep_kernel, dim3(B_ * N_ * UVB + 40), dim3(256), 0, stream,
                     I_src, I_tar, E, dis, nrm, bn_g, bn_b, bn_m, bn_v, w1, w2, conv_w,
                     samp, bns, bnb, w1b, w2b, cwb);
  hipLaunchKernelGGL(conv_kernel, dim3(P_ / 64, B_ * N_), dim3(256), 0, stream,
                     feature, cwb, bns, bnb, val_t);
  hipLaunchKernelGGL(attn_mlp_kernel, dim3(B_ * P_ / 16), dim3(256), 0, stream,
                     val_t, samp, ln1g, ln1b, w1b, w2b, b1, b2, ln2g, ln2b, out);
}